// Round 1
// baseline (404.358 us; speedup 1.0000x reference)
//
#include <hip/hip_runtime.h>

#define B_SZ 256
#define T_SZ 2048
#define D_SZ 64
#define ROWS_PER_BLOCK 256

// Recursive-halving cross-lane column reduce.
// Entry: each of 64 lanes holds cur[0..W_*2) partial column values.
// Exit semantics (applied with W_=32,16,...,1): lane l holds colsum[d=l] in cur[0].
template <int W_>
__device__ __forceinline__ void reduce_step(float* cur, int lane) {
    const bool hi = (lane & W_) != 0;
#pragma unroll
    for (int i = 0; i < W_; ++i) {
        float send = hi ? cur[i] : cur[i + W_];
        float recv = __shfl_xor(send, W_, 64);
        float keep = hi ? cur[i + W_] : cur[i];
        cur[i] = keep + recv;
    }
}

__device__ __forceinline__ float fast_tanh(float s) {
    // 1 - 2/(1+exp(2s)); saturates correctly: exp->inf => 1, exp->0 => -1
    return 1.0f - 2.0f * __builtin_amdgcn_rcpf(1.0f + __expf(2.0f * s));
}

// Kernel 1: S[b][d] = sum_t exp(tanh(x[b,t,:]@W[:,d] + bias[t,d]))
__global__ __launch_bounds__(256) void tca_colsum(const float* __restrict__ x,
                                                  const float* __restrict__ W,
                                                  const float* __restrict__ bias,
                                                  float* __restrict__ S) {
    const int blk = blockIdx.x;
    const int bb = blk / (T_SZ / ROWS_PER_BLOCK);
    const int tchunk = blk % (T_SZ / ROWS_PER_BLOCK);
    const int t = tchunk * ROWS_PER_BLOCK + threadIdx.x;
    const size_t row = (size_t)bb * T_SZ + t;
    const float4* xr = (const float4*)(x + row * D_SZ);
    const float4* br = (const float4*)(bias + (size_t)t * D_SZ);

    float acc[D_SZ];
#pragma unroll
    for (int d = 0; d < D_SZ; ++d) acc[d] = 0.0f;

#pragma unroll
    for (int kk = 0; kk < D_SZ / 4; ++kk) {
        const float4 xq = xr[kk];
        const float xv[4] = {xq.x, xq.y, xq.z, xq.w};
#pragma unroll
        for (int j = 0; j < 4; ++j) {
            const int k = kk * 4 + j;
#pragma unroll
            for (int d = 0; d < D_SZ; ++d) acc[d] += xv[j] * W[k * D_SZ + d];
        }
    }

    // p = exp(tanh(acc + bias)), reuse acc storage
#pragma unroll
    for (int dd = 0; dd < D_SZ / 4; ++dd) {
        const float4 bq = br[dd];
        const float bv[4] = {bq.x, bq.y, bq.z, bq.w};
#pragma unroll
        for (int j = 0; j < 4; ++j) {
            const int d = dd * 4 + j;
            acc[d] = __expf(fast_tanh(acc[d] + bv[j]));
        }
    }

    const int lane = threadIdx.x & 63;
    reduce_step<32>(acc, lane);
    reduce_step<16>(acc, lane);
    reduce_step<8>(acc, lane);
    reduce_step<4>(acc, lane);
    reduce_step<2>(acc, lane);
    reduce_step<1>(acc, lane);
    // lane l now holds colsum for d = l over this block's 64-row wave slice... per wave.
    atomicAdd(&S[bb * D_SZ + lane], acc[0]);
}

// Kernel 2: out[b,t,d] = x[b,t,d] * exp(tanh(x@W+b)[b,t,d]) / S[b,d]
__global__ __launch_bounds__(256) void tca_out(const float* __restrict__ x,
                                               const float* __restrict__ W,
                                               const float* __restrict__ bias,
                                               const float* __restrict__ S,
                                               float* __restrict__ out) {
    const int blk = blockIdx.x;
    const int bb = blk / (T_SZ / ROWS_PER_BLOCK);
    const int tchunk = blk % (T_SZ / ROWS_PER_BLOCK);
    const int t = tchunk * ROWS_PER_BLOCK + threadIdx.x;
    const size_t row = (size_t)bb * T_SZ + t;
    const float4* xr = (const float4*)(x + row * D_SZ);
    const float4* br = (const float4*)(bias + (size_t)t * D_SZ);
    const float* Srow = S + bb * D_SZ;

    float acc[D_SZ];
#pragma unroll
    for (int d = 0; d < D_SZ; ++d) acc[d] = 0.0f;

#pragma unroll
    for (int kk = 0; kk < D_SZ / 4; ++kk) {
        const float4 xq = xr[kk];
        const float xv[4] = {xq.x, xq.y, xq.z, xq.w};
#pragma unroll
        for (int j = 0; j < 4; ++j) {
            const int k = kk * 4 + j;
#pragma unroll
            for (int d = 0; d < D_SZ; ++d) acc[d] += xv[j] * W[k * D_SZ + d];
        }
    }

    float4* outr = (float4*)(out + row * D_SZ);
#pragma unroll
    for (int dd = 0; dd < D_SZ / 4; ++dd) {
        const float4 bq = br[dd];
        const float4 xq = xr[dd];
        const float bv[4] = {bq.x, bq.y, bq.z, bq.w};
        const float xv[4] = {xq.x, xq.y, xq.z, xq.w};
        float ov[4];
#pragma unroll
        for (int j = 0; j < 4; ++j) {
            const int d = dd * 4 + j;
            const float p = __expf(fast_tanh(acc[d] + bv[j]));
            const float a = p * __builtin_amdgcn_rcpf(Srow[d]);
            ov[j] = xv[j] * a;
        }
        float4 o;
        o.x = ov[0]; o.y = ov[1]; o.z = ov[2]; o.w = ov[3];
        outr[dd] = o;
    }
}

extern "C" void kernel_launch(void* const* d_in, const int* in_sizes, int n_in,
                              void* d_out, int out_size, void* d_ws, size_t ws_size,
                              hipStream_t stream) {
    const float* x = (const float*)d_in[0];
    const float* W = (const float*)d_in[1];
    const float* bias = (const float*)d_in[2];
    float* out = (float*)d_out;
    float* S = (float*)d_ws;  // B*D floats = 64 KB

    hipMemsetAsync(S, 0, B_SZ * D_SZ * sizeof(float), stream);

    const dim3 grid(B_SZ * T_SZ / ROWS_PER_BLOCK);
    const dim3 block(ROWS_PER_BLOCK);
    tca_colsum<<<grid, block, 0, stream>>>(x, W, bias, S);
    tca_out<<<grid, block, 0, stream>>>(x, W, bias, S, out);
}